// Round 12
// baseline (1170.775 us; speedup 1.0000x reference)
//
#include <hip/hip_runtime.h>
#include <math.h>

#define T_ 512
#define B_ 32
#define E_ 768
#define H_ 100
#define G_ 400      // 4*H gates per direction
#define N_ 16384    // B*T
#define K_ 10
#define CL_ 128     // viterbi chunk length
#define NC_ 128     // number of chunks
#define START_ 8
#define STOP_ 9
#define NEG_ -10000.0f

#define KT_ 24      // 768/32 k-tiles
#define MT_ 1024    // 16384/16 m-subtiles
#define NT_ 52      // 832/16 n-subtiles (800 padded to 832)

typedef __bf16 bf16;
typedef __attribute__((ext_vector_type(8))) __bf16 bf16x8;
typedef __attribute__((ext_vector_type(4))) float f32x4;

// ---------------------------------------------------------------------------
// prep_A: embeds (fp32, [B][T][E], row m = t*B+b) -> hi/lo bf16 in
// MFMA-fragment-linear layout.
// ---------------------------------------------------------------------------
__global__ __launch_bounds__(256) void prep_A(
    const float* __restrict__ embeds, bf16* __restrict__ Ah, bf16* __restrict__ Al)
{
  int gid = blockIdx.x * 256 + threadIdx.x;          // < MT_*KT_*64
  int mt = gid / (KT_ * 64);
  int rem = gid - mt * (KT_ * 64);
  int kt = rem >> 6, l = rem & 63;
  int row = mt * 16 + (l & 15);
  int t = row >> 5, b = row & 31;
  int e0 = kt * 32 + (l >> 4) * 8;
  const float* src = embeds + (size_t)(b * T_ + t) * E_ + e0;
  float4 f0 = *(const float4*)src;
  float4 f1 = *(const float4*)(src + 4);
  float fv[8] = {f0.x, f0.y, f0.z, f0.w, f1.x, f1.y, f1.z, f1.w};
  bf16x8 h, lo;
  #pragma unroll
  for (int j = 0; j < 8; j++) {
    bf16 hh = (bf16)fv[j];
    h[j] = hh;
    lo[j] = (bf16)(fv[j] - (float)hh);
  }
  *(bf16x8*)(Ah + (size_t)gid * 8) = h;
  *(bf16x8*)(Al + (size_t)gid * 8) = lo;
}

// ---------------------------------------------------------------------------
// prep_B: W_ih_f/W_ih_b -> fragment-linear hi/lo bf16 (B[k][n]=W[n][k]).
// ---------------------------------------------------------------------------
__global__ __launch_bounds__(256) void prep_B(
    const float* __restrict__ Wf, const float* __restrict__ Wb,
    bf16* __restrict__ Bh, bf16* __restrict__ Bl)
{
  int gid = blockIdx.x * 256 + threadIdx.x;          // < NT_*KT_*64
  int nt = gid / (KT_ * 64);
  int rem = gid - nt * (KT_ * 64);
  int kt = rem >> 6, l = rem & 63;
  int n = nt * 16 + (l & 15);
  int k0 = kt * 32 + (l >> 4) * 8;
  float fv[8] = {0.f,0.f,0.f,0.f,0.f,0.f,0.f,0.f};
  if (n < G_) {
    const float* src = Wf + (size_t)n * E_ + k0;
    float4 f0 = *(const float4*)src; float4 f1 = *(const float4*)(src + 4);
    fv[0]=f0.x; fv[1]=f0.y; fv[2]=f0.z; fv[3]=f0.w;
    fv[4]=f1.x; fv[5]=f1.y; fv[6]=f1.z; fv[7]=f1.w;
  } else if (n < 2*G_) {
    const float* src = Wb + (size_t)(n - G_) * E_ + k0;
    float4 f0 = *(const float4*)src; float4 f1 = *(const float4*)(src + 4);
    fv[0]=f0.x; fv[1]=f0.y; fv[2]=f0.z; fv[3]=f0.w;
    fv[4]=f1.x; fv[5]=f1.y; fv[6]=f1.z; fv[7]=f1.w;
  }
  bf16x8 h, lo;
  #pragma unroll
  for (int j = 0; j < 8; j++) {
    bf16 hh = (bf16)fv[j];
    h[j] = hh;
    lo[j] = (bf16)(fv[j] - (float)hh);
  }
  *(bf16x8*)(Bh + (size_t)gid * 8) = h;
  *(bf16x8*)(Bl + (size_t)gid * 8) = lo;
}

// ---------------------------------------------------------------------------
// xw_mfma: C[16384][832] = A . B, split-bf16 (3 MFMA). Linear xw epilogue
// (round-4 verified). 64x64 tile, 4 waves 2x2.
// ---------------------------------------------------------------------------
__global__ __launch_bounds__(256) void xw_mfma(
    const bf16* __restrict__ Ah, const bf16* __restrict__ Al,
    const bf16* __restrict__ Bh, const bf16* __restrict__ Bl,
    const float* __restrict__ bif, const float* __restrict__ bhf,
    const float* __restrict__ bib, const float* __restrict__ bhb,
    float* __restrict__ xw_f, float* __restrict__ xw_b)
{
  __shared__ __align__(16) bf16 SA[2][4][512];
  __shared__ __align__(16) bf16 SB[2][4][512];
  int tid = threadIdx.x;
  int wave = tid >> 6, lane = tid & 63;
  int wm = wave & 1, wn = wave >> 1;
  int mt0 = blockIdx.x * 4, nt0 = blockIdx.y * 4;

  f32x4 acc[2][2];
  #pragma unroll
  for (int mi = 0; mi < 2; mi++)
    #pragma unroll
    for (int ni = 0; ni < 2; ni++)
      #pragma unroll
      for (int q = 0; q < 4; q++) acc[mi][ni][q] = 0.f;

  #pragma unroll 1
  for (int kt = 0; kt < KT_; kt++) {
    #pragma unroll
    for (int i = 0; i < 4; i++) {
      int u = i * 256 + tid;
      int c = u >> 6, l64 = u & 63;
      const bf16* g; bf16* d;
      if (c < 8) {
        int ms = c >> 1;
        const bf16* base = (c & 1) ? Al : Ah;
        g = base + ((size_t)(mt0 + ms) * KT_ + kt) * 512 + l64 * 8;
        d = &SA[c & 1][ms][l64 * 8];
      } else {
        int cc = c - 8;
        int ns = cc >> 1;
        const bf16* base = (cc & 1) ? Bl : Bh;
        g = base + ((size_t)(nt0 + ns) * KT_ + kt) * 512 + l64 * 8;
        d = &SB[cc & 1][ns][l64 * 8];
      }
      *(bf16x8*)d = *(const bf16x8*)g;
    }
    __syncthreads();
    bf16x8 a_h[2], a_l[2], b_h[2], b_l[2];
    #pragma unroll
    for (int mi = 0; mi < 2; mi++) {
      int ms = wm * 2 + mi;
      a_h[mi] = *(const bf16x8*)&SA[0][ms][lane * 8];
      a_l[mi] = *(const bf16x8*)&SA[1][ms][lane * 8];
    }
    #pragma unroll
    for (int ni = 0; ni < 2; ni++) {
      int ns = wn * 2 + ni;
      b_h[ni] = *(const bf16x8*)&SB[0][ns][lane * 8];
      b_l[ni] = *(const bf16x8*)&SB[1][ns][lane * 8];
    }
    #pragma unroll
    for (int mi = 0; mi < 2; mi++)
      #pragma unroll
      for (int ni = 0; ni < 2; ni++) {
        acc[mi][ni] = __builtin_amdgcn_mfma_f32_16x16x32_bf16(a_h[mi], b_h[ni], acc[mi][ni], 0, 0, 0);
        acc[mi][ni] = __builtin_amdgcn_mfma_f32_16x16x32_bf16(a_l[mi], b_h[ni], acc[mi][ni], 0, 0, 0);
        acc[mi][ni] = __builtin_amdgcn_mfma_f32_16x16x32_bf16(a_h[mi], b_l[ni], acc[mi][ni], 0, 0, 0);
      }
    __syncthreads();
  }

  int m_base = blockIdx.x * 64 + wm * 32;
  int n_base = blockIdx.y * 64 + wn * 32;
  #pragma unroll
  for (int mi = 0; mi < 2; mi++)
    #pragma unroll
    for (int ni = 0; ni < 2; ni++)
      #pragma unroll
      for (int r = 0; r < 4; r++) {
        int m = m_base + mi * 16 + (lane >> 4) * 4 + r;   // C/D: row=(lane>>4)*4+reg
        int c = n_base + ni * 16 + (lane & 15);           //      col=lane&15
        float v = acc[mi][ni][r];
        if (c < G_) {
          xw_f[(size_t)m * G_ + c] = v + bif[c] + bhf[c];
        } else if (c < 2 * G_) {
          int cc = c - G_;
          xw_b[(size_t)m * G_ + cc] = v + bib[cc] + bhb[cc];
        }
      }
}

// ---------------------------------------------------------------------------
// K2: LSTM recurrence v4. 64 wgs = 2 dirs x 32 batches, 448 threads.
// W_hh staged in LDS (Ws[400][100] fp32, 160 KB): row stride 400 B is
// 16B-aligned and bank-uniform for ds_read_b128 (4*lane mod 32 tiles all
// banks, 8 dwords/bank = same load as contiguous ideal). Round-4 verified
// 2-barrier structure (g_s gather, tid<100 activations).
// ---------------------------------------------------------------------------
__global__ __launch_bounds__(448) void lstm_rec(
    const float* __restrict__ xw_f, const float* __restrict__ xw_b,
    const float* __restrict__ Whh_f, const float* __restrict__ Whh_b,
    float* __restrict__ hf, float* __restrict__ hb)
{
  int wg = blockIdx.x;
  int dir = wg >> 5, b = wg & 31;
  const float* xw  = dir ? xw_b : xw_f;
  const float* Whh = dir ? Whh_b : Whh_f;
  float* hout      = dir ? hb : hf;

  __shared__ __align__(16) float Ws[G_][H_];   // 160,000 B
  __shared__ __align__(16) float h_s[H_];      // 400 B
  __shared__ float g_s[G_];                    // 1,600 B  (total 162,000 <= 163,840)
  int tid = threadIdx.x;

  // Stage W_hh -> LDS, coalesced (rows contiguous: Ws[r][k] = Whh[r*100+k]).
  for (int idx = tid; idx < G_ * H_; idx += 448)
    ((float*)Ws)[idx] = Whh[idx];
  if (tid < H_) h_s[tid] = 0.f;
  float c = 0.f;
  __syncthreads();

  int t  = dir ? (T_ - 1) : 0;
  int dt = dir ? -1 : 1;
  float xw_cur = (tid < G_) ? xw[(size_t)(t * B_ + b) * G_ + tid] : 0.f;

  #pragma unroll 1
  for (int s = 0; s < T_; s++) {
    int tn = t + dt;
    float xw_next = 0.f;
    if (s < T_ - 1 && tid < G_) xw_next = xw[(size_t)(tn * B_ + b) * G_ + tid];

    if (tid < G_) {
      float a0 = xw_cur, a1 = 0.f, a2 = 0.f, a3 = 0.f;
      const float4* wrow = (const float4*)&Ws[tid][0];   // 400B stride, 16B aligned
      const float4* h4 = (const float4*)h_s;
      #pragma unroll
      for (int i = 0; i < 25; i++) {
        float4 w = wrow[i];
        float4 hv = h4[i];
        a0 += w.x * hv.x;
        a1 += w.y * hv.y;
        a2 += w.z * hv.z;
        a3 += w.w * hv.w;
      }
      g_s[tid] = (a0 + a1) + (a2 + a3);
    }
    __syncthreads();
    if (tid < H_) {
      float gi = g_s[tid], gf = g_s[H_ + tid], gg = g_s[2*H_ + tid], go = g_s[3*H_ + tid];
      float si = __builtin_amdgcn_rcpf(1.f + __expf(-gi));
      float sf = __builtin_amdgcn_rcpf(1.f + __expf(-gf));
      float so = __builtin_amdgcn_rcpf(1.f + __expf(-go));
      float tg = 1.f - 2.f * __builtin_amdgcn_rcpf(1.f + __expf(2.f * gg));
      c = sf * c + si * tg;
      float th = 1.f - 2.f * __builtin_amdgcn_rcpf(1.f + __expf(2.f * c));
      float hv = so * th;
      h_s[tid] = hv;
      hout[(size_t)(t * B_ + b) * H_ + tid] = hv;
    }
    __syncthreads();
    xw_cur = xw_next;
    t = tn;
  }
}

// ---------------------------------------------------------------------------
// K3: feats[n][k] = b_out[k] + W_out[k,:100].hf + W_out[k,100:].hb
// ---------------------------------------------------------------------------
__global__ __launch_bounds__(256) void feats_kernel(
    const float* __restrict__ hf, const float* __restrict__ hb,
    const float* __restrict__ W_out, const float* __restrict__ b_out,
    float* __restrict__ feats)
{
  int id = blockIdx.x * blockDim.x + threadIdx.x;
  int n = id >> 4, k = id & 15;
  if (n >= N_ || k >= K_) return;
  int b = n / T_, t = n % T_;
  const float* hfp = hf + (size_t)(t * B_ + b) * H_;
  const float* hbp = hb + (size_t)(t * B_ + b) * H_;
  const float* w0 = W_out + k * (2 * H_);
  float acc = b_out[k];
  #pragma unroll 4
  for (int j = 0; j < H_; j++) acc += w0[j] * hfp[j];
  #pragma unroll 4
  for (int j = 0; j < H_; j++) acc += w0[H_ + j] * hbp[j];
  feats[n * K_ + k] = acc;
}

// ---------------------------------------------------------------------------
// Viterbi, chunked (exact in max-plus semiring; verified absmax 0.0).
// ---------------------------------------------------------------------------
__global__ __launch_bounds__(128) void vit_chunkmat(
    const float* __restrict__ feats, const float* __restrict__ trans,
    float* __restrict__ Mout)
{
  int cix = blockIdx.x, tid = threadIdx.x;
  __shared__ float tr[K_][K_];
  __shared__ float fe[CL_][K_];
  __shared__ float M[2][K_][K_ + 2];
  if (tid < K_ * K_) tr[tid / K_][tid % K_] = trans[tid];
  for (int idx = tid; idx < CL_ * K_; idx += 128)
    fe[idx / K_][idx % K_] = feats[cix * CL_ * K_ + idx];
  __syncthreads();
  int i = tid / K_, j = tid % K_;
  int p = 0;
  if (tid < K_ * K_) M[0][i][j] = tr[i][j] + fe[0][i];
  __syncthreads();
  #pragma unroll 1
  for (int s = 1; s < CL_; s++) {
    if (tid < K_ * K_) {
      float v = tr[i][0] + M[p][0][j];
      #pragma unroll
      for (int k = 1; k < K_; k++) v = fmaxf(v, tr[i][k] + M[p][k][j]);
      M[p ^ 1][i][j] = v + fe[s][i];
    }
    __syncthreads();
    p ^= 1;
  }
  if (tid < K_ * K_) Mout[cix * (K_ * K_) + tid] = M[p][i][j];
}

__global__ __launch_bounds__(128) void vit_scan(
    const float* __restrict__ Mall, const float* __restrict__ trans,
    float* __restrict__ Efv, int* __restrict__ best_out,
    float* __restrict__ out)
{
  __shared__ float Ms[NC_][K_ * K_];
  __shared__ float F[K_], Fn[K_];
  int tid = threadIdx.x;
  for (int idx = tid; idx < NC_ * K_ * K_; idx += 128)
    Ms[idx / (K_ * K_)][idx % (K_ * K_)] = Mall[idx];
  if (tid < K_) F[tid] = (tid == START_) ? 0.f : NEG_;
  __syncthreads();
  #pragma unroll 1
  for (int cix = 0; cix < NC_; cix++) {
    if (tid < K_) {
      Efv[cix * K_ + tid] = F[tid];
      float v = Ms[cix][tid * K_ + 0] + F[0];
      #pragma unroll
      for (int j = 1; j < K_; j++) v = fmaxf(v, Ms[cix][tid * K_ + j] + F[j]);
      Fn[tid] = v;
    }
    __syncthreads();
    if (tid < K_) F[tid] = Fn[tid];
    __syncthreads();
  }
  if (tid == 0) {
    float best = -1e30f; int bi = 0;
    for (int i = 0; i < K_; i++) {
      float term = (i == STOP_ || i == START_) ? NEG_ : (F[i] + trans[STOP_ * K_ + i]);
      if (term > best) { best = term; bi = i; }
    }
    out[0] = best;
    best_out[0] = bi;
  }
}

// vit_bp + chunkmap merged: bp replay, then per-chunk backtrace map G.
__global__ __launch_bounds__(64) void vit_bp(
    const float* __restrict__ feats, const float* __restrict__ trans,
    const float* __restrict__ Efv, unsigned char* __restrict__ bp,
    unsigned char* __restrict__ G)
{
  int cix = blockIdx.x, tid = threadIdx.x;
  __shared__ float tr[K_][K_];
  __shared__ float fe[CL_][K_];
  __shared__ float fv[K_], fvn[K_];
  __shared__ unsigned char bps[CL_][K_];
  for (int idx = tid; idx < K_ * K_; idx += 64) tr[idx / K_][idx % K_] = trans[idx];
  for (int idx = tid; idx < CL_ * K_; idx += 64)
    fe[idx / K_][idx % K_] = feats[cix * CL_ * K_ + idx];
  if (tid < K_) fv[tid] = Efv[cix * K_ + tid];
  __syncthreads();
  #pragma unroll 1
  for (int s = 0; s < CL_; s++) {
    if (tid < K_) {
      int i = tid;
      float best = fv[0] + tr[i][0]; int bj = 0;
      #pragma unroll
      for (int j = 1; j < K_; j++) {
        float v = fv[j] + tr[i][j];
        if (v > best) { best = v; bj = j; }
      }
      bp[(size_t)(cix * CL_ + s) * K_ + i] = (unsigned char)bj;
      bps[s][i] = (unsigned char)bj;
      fvn[i] = best + fe[s][i];
    }
    __syncthreads();
    if (tid < K_) fv[tid] = fvn[tid];
    __syncthreads();
  }
  if (tid < K_) {
    int tag = tid;
    #pragma unroll 1
    for (int s = CL_ - 1; s >= 0; s--) tag = bps[s][tag];
    G[cix * K_ + tid] = (unsigned char)tag;
  }
}

__global__ __launch_bounds__(64) void vit_bound(
    const unsigned char* __restrict__ G, const int* __restrict__ best,
    unsigned char* __restrict__ tbound)
{
  __shared__ unsigned char Gs[NC_][K_];
  int tid = threadIdx.x;
  for (int idx = tid; idx < NC_ * K_; idx += 64) Gs[idx / K_][idx % K_] = G[idx];
  __syncthreads();
  if (tid == 0) {
    int tag = best[0];
    tbound[NC_ - 1] = (unsigned char)tag;
    #pragma unroll 1
    for (int cix = NC_ - 1; cix >= 1; cix--) {
      tag = Gs[cix][tag];
      tbound[cix - 1] = (unsigned char)tag;
    }
  }
}

__global__ __launch_bounds__(64) void vit_path(
    const unsigned char* __restrict__ bp, const unsigned char* __restrict__ tbound,
    float* __restrict__ out)
{
  int cix = blockIdx.x, tid = threadIdx.x;
  __shared__ unsigned char bps[CL_][K_];
  for (int idx = tid; idx < CL_ * K_; idx += 64)
    bps[idx / K_][idx % K_] = bp[(size_t)cix * CL_ * K_ + idx];
  __syncthreads();
  if (tid == 0) {
    int tag = tbound[cix];
    out[1 + cix * CL_ + (CL_ - 1)] = (float)tag;
    #pragma unroll 1
    for (int s = CL_ - 1; s >= 1; s--) {
      tag = bps[s][tag];
      out[1 + cix * CL_ + s - 1] = (float)tag;
    }
  }
}

// ---------------------------------------------------------------------------
extern "C" void kernel_launch(void* const* d_in, const int* in_sizes, int n_in,
                              void* d_out, int out_size, void* d_ws, size_t ws_size,
                              hipStream_t stream) {
  const float* embeds = (const float*)d_in[0];
  const float* W_ih_f = (const float*)d_in[1];
  const float* W_hh_f = (const float*)d_in[2];
  const float* b_ih_f = (const float*)d_in[3];
  const float* b_hh_f = (const float*)d_in[4];
  const float* W_ih_b = (const float*)d_in[5];
  const float* W_hh_b = (const float*)d_in[6];
  const float* b_ih_b = (const float*)d_in[7];
  const float* b_hh_b = (const float*)d_in[8];
  const float* W_out  = (const float*)d_in[9];
  const float* b_out  = (const float*)d_in[10];
  const float* trans  = (const float*)d_in[11];
  float* out = (float*)d_out;

  char* ws = (char*)d_ws;
  size_t off = 0;
  float* xw_f = (float*)(ws + off); off += (size_t)N_ * G_ * 4;              // 26.2 MB
  float* xw_b = (float*)(ws + off); off += (size_t)N_ * G_ * 4;              // 26.2 MB
  bf16* Bh = (bf16*)(ws + off); off += (size_t)NT_ * KT_ * 512 * 2;          // 1.28 MB
  bf16* Bl = (bf16*)(ws + off); off += (size_t)NT_ * KT_ * 512 * 2;          // 1.28 MB
  // region R: Ah/Al live only until xw_mfma completes; post-GEMM buffers
  // alias the same region.
  char* R = ws + off;
  bf16* Ah = (bf16*)R;
  bf16* Al = (bf16*)(R + (size_t)MT_ * KT_ * 512 * 2);                       // +25.2 MB
  size_t ro = 0;
  float* hf   = (float*)(R + ro); ro += (size_t)N_ * H_ * 4;                 // 6.55 MB
  float* hb   = (float*)(R + ro); ro += (size_t)N_ * H_ * 4;                 // 6.55 MB
  float* feats= (float*)(R + ro); ro += (size_t)N_ * K_ * 4;                 // 655 KB
  float* Mall = (float*)(R + ro); ro += (size_t)NC_ * K_ * K_ * 4;
  float* Efv  = (float*)(R + ro); ro += (size_t)NC_ * K_ * 4;
  unsigned char* bp = (unsigned char*)(R + ro); ro += ((size_t)N_ * K_ + 255) & ~255ull;
  unsigned char* G  = (unsigned char*)(R + ro); ro += ((size_t)NC_ * K_ + 255) & ~255ull;
  unsigned char* tb = (unsigned char*)(R + ro); ro += 256;
  int* best = (int*)(R + ro); ro += 256;

  prep_A<<<MT_ * KT_ * 64 / 256, 256, 0, stream>>>(embeds, Ah, Al);
  prep_B<<<NT_ * KT_ * 64 / 256, 256, 0, stream>>>(W_ih_f, W_ih_b, Bh, Bl);
  xw_mfma<<<dim3(N_ / 64, 13), 256, 0, stream>>>(Ah, Al, Bh, Bl,
      b_ih_f, b_hh_f, b_ih_b, b_hh_b, xw_f, xw_b);
  lstm_rec<<<64, 448, 0, stream>>>(xw_f, xw_b, W_hh_f, W_hh_b, hf, hb);
  feats_kernel<<<(N_ * 16) / 256, 256, 0, stream>>>(hf, hb, W_out, b_out, feats);
  vit_chunkmat<<<NC_, 128, 0, stream>>>(feats, trans, Mall);
  vit_scan<<<1, 128, 0, stream>>>(Mall, trans, Efv, best, out);
  vit_bp<<<NC_, 64, 0, stream>>>(feats, trans, Efv, bp, G);
  vit_bound<<<1, 64, 0, stream>>>(G, best, tb);
  vit_path<<<NC_, 64, 0, stream>>>(bp, tb, out);
}

// Round 14
// 755.677 us; speedup vs baseline: 1.5493x; 1.5493x over previous
//
#include <hip/hip_runtime.h>
#include <math.h>

#define T_ 512
#define B_ 32
#define E_ 768
#define H_ 100
#define G_ 400      // 4*H gates per direction
#define N_ 16384    // B*T
#define K_ 10
#define CL_ 128     // viterbi chunk length
#define NC_ 128     // number of chunks
#define START_ 8
#define STOP_ 9
#define NEG_ -10000.0f

#define KT_ 24      // 768/32 k-tiles
#define MT_ 1024    // 16384/16 m-subtiles
#define NT_ 52      // 832/16 n-subtiles (800 padded to 832)

typedef __bf16 bf16;
typedef __attribute__((ext_vector_type(8))) __bf16 bf16x8;
typedef __attribute__((ext_vector_type(4))) float f32x4;

// ---------------------------------------------------------------------------
// prep_A: embeds (fp32, [B][T][E], row m = t*B+b) -> hi/lo bf16 in
// MFMA-fragment-linear layout.
// ---------------------------------------------------------------------------
__global__ __launch_bounds__(256) void prep_A(
    const float* __restrict__ embeds, bf16* __restrict__ Ah, bf16* __restrict__ Al)
{
  int gid = blockIdx.x * 256 + threadIdx.x;          // < MT_*KT_*64
  int mt = gid / (KT_ * 64);
  int rem = gid - mt * (KT_ * 64);
  int kt = rem >> 6, l = rem & 63;
  int row = mt * 16 + (l & 15);
  int t = row >> 5, b = row & 31;
  int e0 = kt * 32 + (l >> 4) * 8;
  const float* src = embeds + (size_t)(b * T_ + t) * E_ + e0;
  float4 f0 = *(const float4*)src;
  float4 f1 = *(const float4*)(src + 4);
  float fv[8] = {f0.x, f0.y, f0.z, f0.w, f1.x, f1.y, f1.z, f1.w};
  bf16x8 h, lo;
  #pragma unroll
  for (int j = 0; j < 8; j++) {
    bf16 hh = (bf16)fv[j];
    h[j] = hh;
    lo[j] = (bf16)(fv[j] - (float)hh);
  }
  *(bf16x8*)(Ah + (size_t)gid * 8) = h;
  *(bf16x8*)(Al + (size_t)gid * 8) = lo;
}

// ---------------------------------------------------------------------------
// prep_B: W_ih_f/W_ih_b -> fragment-linear hi/lo bf16 (B[k][n]=W[n][k]).
// ---------------------------------------------------------------------------
__global__ __launch_bounds__(256) void prep_B(
    const float* __restrict__ Wf, const float* __restrict__ Wb,
    bf16* __restrict__ Bh, bf16* __restrict__ Bl)
{
  int gid = blockIdx.x * 256 + threadIdx.x;          // < NT_*KT_*64
  int nt = gid / (KT_ * 64);
  int rem = gid - nt * (KT_ * 64);
  int kt = rem >> 6, l = rem & 63;
  int n = nt * 16 + (l & 15);
  int k0 = kt * 32 + (l >> 4) * 8;
  float fv[8] = {0.f,0.f,0.f,0.f,0.f,0.f,0.f,0.f};
  if (n < G_) {
    const float* src = Wf + (size_t)n * E_ + k0;
    float4 f0 = *(const float4*)src; float4 f1 = *(const float4*)(src + 4);
    fv[0]=f0.x; fv[1]=f0.y; fv[2]=f0.z; fv[3]=f0.w;
    fv[4]=f1.x; fv[5]=f1.y; fv[6]=f1.z; fv[7]=f1.w;
  } else if (n < 2*G_) {
    const float* src = Wb + (size_t)(n - G_) * E_ + k0;
    float4 f0 = *(const float4*)src; float4 f1 = *(const float4*)(src + 4);
    fv[0]=f0.x; fv[1]=f0.y; fv[2]=f0.z; fv[3]=f0.w;
    fv[4]=f1.x; fv[5]=f1.y; fv[6]=f1.z; fv[7]=f1.w;
  }
  bf16x8 h, lo;
  #pragma unroll
  for (int j = 0; j < 8; j++) {
    bf16 hh = (bf16)fv[j];
    h[j] = hh;
    lo[j] = (bf16)(fv[j] - (float)hh);
  }
  *(bf16x8*)(Bh + (size_t)gid * 8) = h;
  *(bf16x8*)(Bl + (size_t)gid * 8) = lo;
}

// ---------------------------------------------------------------------------
// xw_mfma: C[16384][832] = A . B, split-bf16 (3 MFMA). Linear xw epilogue
// (verified r4/r11/r12). 64x64 tile, 4 waves 2x2.
// ---------------------------------------------------------------------------
__global__ __launch_bounds__(256) void xw_mfma(
    const bf16* __restrict__ Ah, const bf16* __restrict__ Al,
    const bf16* __restrict__ Bh, const bf16* __restrict__ Bl,
    const float* __restrict__ bif, const float* __restrict__ bhf,
    const float* __restrict__ bib, const float* __restrict__ bhb,
    float* __restrict__ xw_f, float* __restrict__ xw_b)
{
  __shared__ __align__(16) bf16 SA[2][4][512];
  __shared__ __align__(16) bf16 SB[2][4][512];
  int tid = threadIdx.x;
  int wave = tid >> 6, lane = tid & 63;
  int wm = wave & 1, wn = wave >> 1;
  int mt0 = blockIdx.x * 4, nt0 = blockIdx.y * 4;

  f32x4 acc[2][2];
  #pragma unroll
  for (int mi = 0; mi < 2; mi++)
    #pragma unroll
    for (int ni = 0; ni < 2; ni++)
      #pragma unroll
      for (int q = 0; q < 4; q++) acc[mi][ni][q] = 0.f;

  #pragma unroll 1
  for (int kt = 0; kt < KT_; kt++) {
    #pragma unroll
    for (int i = 0; i < 4; i++) {
      int u = i * 256 + tid;
      int c = u >> 6, l64 = u & 63;
      const bf16* g; bf16* d;
      if (c < 8) {
        int ms = c >> 1;
        const bf16* base = (c & 1) ? Al : Ah;
        g = base + ((size_t)(mt0 + ms) * KT_ + kt) * 512 + l64 * 8;
        d = &SA[c & 1][ms][l64 * 8];
      } else {
        int cc = c - 8;
        int ns = cc >> 1;
        const bf16* base = (cc & 1) ? Bl : Bh;
        g = base + ((size_t)(nt0 + ns) * KT_ + kt) * 512 + l64 * 8;
        d = &SB[cc & 1][ns][l64 * 8];
      }
      *(bf16x8*)d = *(const bf16x8*)g;
    }
    __syncthreads();
    bf16x8 a_h[2], a_l[2], b_h[2], b_l[2];
    #pragma unroll
    for (int mi = 0; mi < 2; mi++) {
      int ms = wm * 2 + mi;
      a_h[mi] = *(const bf16x8*)&SA[0][ms][lane * 8];
      a_l[mi] = *(const bf16x8*)&SA[1][ms][lane * 8];
    }
    #pragma unroll
    for (int ni = 0; ni < 2; ni++) {
      int ns = wn * 2 + ni;
      b_h[ni] = *(const bf16x8*)&SB[0][ns][lane * 8];
      b_l[ni] = *(const bf16x8*)&SB[1][ns][lane * 8];
    }
    #pragma unroll
    for (int mi = 0; mi < 2; mi++)
      #pragma unroll
      for (int ni = 0; ni < 2; ni++) {
        acc[mi][ni] = __builtin_amdgcn_mfma_f32_16x16x32_bf16(a_h[mi], b_h[ni], acc[mi][ni], 0, 0, 0);
        acc[mi][ni] = __builtin_amdgcn_mfma_f32_16x16x32_bf16(a_l[mi], b_h[ni], acc[mi][ni], 0, 0, 0);
        acc[mi][ni] = __builtin_amdgcn_mfma_f32_16x16x32_bf16(a_h[mi], b_l[ni], acc[mi][ni], 0, 0, 0);
      }
    __syncthreads();
  }

  int m_base = blockIdx.x * 64 + wm * 32;
  int n_base = blockIdx.y * 64 + wn * 32;
  #pragma unroll
  for (int mi = 0; mi < 2; mi++)
    #pragma unroll
    for (int ni = 0; ni < 2; ni++)
      #pragma unroll
      for (int r = 0; r < 4; r++) {
        int m = m_base + mi * 16 + (lane >> 4) * 4 + r;   // C/D: row=(lane>>4)*4+reg
        int c = n_base + ni * 16 + (lane & 15);           //      col=lane&15
        float v = acc[mi][ni][r];
        if (c < G_) {
          xw_f[(size_t)m * G_ + c] = v + bif[c] + bhf[c];
        } else if (c < 2 * G_) {
          int cc = c - G_;
          xw_b[(size_t)m * G_ + cc] = v + bib[cc] + bhb[cc];
        }
      }
}

// ---------------------------------------------------------------------------
// K2: LSTM recurrence v5. 64 wgs = 2 dirs x 32 batches, 832 threads (13 waves).
// Thread (r = tid>>1, q = tid&1) owns row r's chunks c = 2i+q (16B float4
// chunks of the 100-k dot): 13 float4 = 52 VGPRs -- half of the 100 that the
// allocator refused twice (r11: 84, r4: 92 granted). W loaded from global
// ONCE. Per step: 13 broadcast-group ds_read_b128 of h + 52 FMA + 1 shfl.
// q=1's 13th chunk is zero (h_s padded to 112, pad zeroed -> exact).
// ---------------------------------------------------------------------------
__global__ __launch_bounds__(832) void lstm_rec(
    const float* __restrict__ xw_f, const float* __restrict__ xw_b,
    const float* __restrict__ Whh_f, const float* __restrict__ Whh_b,
    float* __restrict__ hf, float* __restrict__ hb)
{
  int wg = blockIdx.x;
  int dir = wg >> 5, b = wg & 31;
  const float* xw  = dir ? xw_b : xw_f;
  const float* Whh = dir ? Whh_b : Whh_f;
  float* hout      = dir ? hb : hf;

  __shared__ __align__(16) float h_s[112];   // 100 + zero pad (chunk 25 safety)
  __shared__ float g_s[G_];
  int tid = threadIdx.x;
  int r = tid >> 1, q = tid & 1;
  bool act = (tid < 2 * G_);                 // 800 dot threads

  // W chunks: c = 2i+q, i = 0..12; q=1 has only 12 real chunks (13th = 0).
  float4 W[13];
  if (act) {
    const float* wr = Whh + (size_t)r * H_;
    #pragma unroll
    for (int i = 0; i < 12; i++) W[i] = *(const float4*)(wr + (2 * i + q) * 4);
    if (q == 0) W[12] = *(const float4*)(wr + 96);
    else        W[12] = make_float4(0.f, 0.f, 0.f, 0.f);
  }
  if (tid < 112) h_s[tid] = 0.f;
  float c = 0.f;
  __syncthreads();

  int t  = dir ? (T_ - 1) : 0;
  int dt = dir ? -1 : 1;
  bool ldx = act && (q == 0);
  float xw_cur = ldx ? xw[(size_t)(t * B_ + b) * G_ + r] : 0.f;

  #pragma unroll 1
  for (int s = 0; s < T_; s++) {
    int tn = t + dt;
    float xw_next = 0.f;
    if (s < T_ - 1 && ldx) xw_next = xw[(size_t)(tn * B_ + b) * G_ + r];

    if (act) {
      float a0 = 0.f, a1 = 0.f, a2 = 0.f, a3 = 0.f;
      const float4* h4 = (const float4*)h_s;
      #pragma unroll
      for (int i = 0; i < 13; i++) {
        float4 w = W[i];
        float4 hv = h4[2 * i + q];           // q=1,i=12 -> chunk 25 = zero pad
        a0 += w.x * hv.x;
        a1 += w.y * hv.y;
        a2 += w.z * hv.z;
        a3 += w.w * hv.w;
      }
      float part = (a0 + a1) + (a2 + a3) + xw_cur;   // xw_cur = 0 for q=1
      part += __shfl_xor(part, 1);
      if (q == 0) g_s[r] = part;
    }
    __syncthreads();
    if (tid < H_) {
      float gi = g_s[tid], gf = g_s[H_ + tid], gg = g_s[2*H_ + tid], go = g_s[3*H_ + tid];
      float si = __builtin_amdgcn_rcpf(1.f + __expf(-gi));
      float sf = __builtin_amdgcn_rcpf(1.f + __expf(-gf));
      float so = __builtin_amdgcn_rcpf(1.f + __expf(-go));
      float tg = 1.f - 2.f * __builtin_amdgcn_rcpf(1.f + __expf(2.f * gg));
      c = sf * c + si * tg;
      float th = 1.f - 2.f * __builtin_amdgcn_rcpf(1.f + __expf(2.f * c));
      float hv = so * th;
      h_s[tid] = hv;
      hout[(size_t)(t * B_ + b) * H_ + tid] = hv;
    }
    __syncthreads();
    xw_cur = xw_next;
    t = tn;
  }
}

// ---------------------------------------------------------------------------
// K3: feats[n][k] = b_out[k] + W_out[k,:100].hf + W_out[k,100:].hb
// ---------------------------------------------------------------------------
__global__ __launch_bounds__(256) void feats_kernel(
    const float* __restrict__ hf, const float* __restrict__ hb,
    const float* __restrict__ W_out, const float* __restrict__ b_out,
    float* __restrict__ feats)
{
  int id = blockIdx.x * blockDim.x + threadIdx.x;
  int n = id >> 4, k = id & 15;
  if (n >= N_ || k >= K_) return;
  int b = n / T_, t = n % T_;
  const float* hfp = hf + (size_t)(t * B_ + b) * H_;
  const float* hbp = hb + (size_t)(t * B_ + b) * H_;
  const float* w0 = W_out + k * (2 * H_);
  float acc = b_out[k];
  #pragma unroll 4
  for (int j = 0; j < H_; j++) acc += w0[j] * hfp[j];
  #pragma unroll 4
  for (int j = 0; j < H_; j++) acc += w0[H_ + j] * hbp[j];
  feats[n * K_ + k] = acc;
}

// ---------------------------------------------------------------------------
// Viterbi, chunked (exact in max-plus semiring; verified absmax 0.0).
// ---------------------------------------------------------------------------
__global__ __launch_bounds__(128) void vit_chunkmat(
    const float* __restrict__ feats, const float* __restrict__ trans,
    float* __restrict__ Mout)
{
  int cix = blockIdx.x, tid = threadIdx.x;
  __shared__ float tr[K_][K_];
  __shared__ float fe[CL_][K_];
  __shared__ float M[2][K_][K_ + 2];
  if (tid < K_ * K_) tr[tid / K_][tid % K_] = trans[tid];
  for (int idx = tid; idx < CL_ * K_; idx += 128)
    fe[idx / K_][idx % K_] = feats[cix * CL_ * K_ + idx];
  __syncthreads();
  int i = tid / K_, j = tid % K_;
  int p = 0;
  if (tid < K_ * K_) M[0][i][j] = tr[i][j] + fe[0][i];
  __syncthreads();
  #pragma unroll 1
  for (int s = 1; s < CL_; s++) {
    if (tid < K_ * K_) {
      float v = tr[i][0] + M[p][0][j];
      #pragma unroll
      for (int k = 1; k < K_; k++) v = fmaxf(v, tr[i][k] + M[p][k][j]);
      M[p ^ 1][i][j] = v + fe[s][i];
    }
    __syncthreads();
    p ^= 1;
  }
  if (tid < K_ * K_) Mout[cix * (K_ * K_) + tid] = M[p][i][j];
}

__global__ __launch_bounds__(128) void vit_scan(
    const float* __restrict__ Mall, const float* __restrict__ trans,
    float* __restrict__ Efv, int* __restrict__ best_out,
    float* __restrict__ out)
{
  __shared__ float Ms[NC_][K_ * K_];
  __shared__ float F[K_], Fn[K_];
  int tid = threadIdx.x;
  for (int idx = tid; idx < NC_ * K_ * K_; idx += 128)
    Ms[idx / (K_ * K_)][idx % (K_ * K_)] = Mall[idx];
  if (tid < K_) F[tid] = (tid == START_) ? 0.f : NEG_;
  __syncthreads();
  #pragma unroll 1
  for (int cix = 0; cix < NC_; cix++) {
    if (tid < K_) {
      Efv[cix * K_ + tid] = F[tid];
      float v = Ms[cix][tid * K_ + 0] + F[0];
      #pragma unroll
      for (int j = 1; j < K_; j++) v = fmaxf(v, Ms[cix][tid * K_ + j] + F[j]);
      Fn[tid] = v;
    }
    __syncthreads();
    if (tid < K_) F[tid] = Fn[tid];
    __syncthreads();
  }
  if (tid == 0) {
    float best = -1e30f; int bi = 0;
    for (int i = 0; i < K_; i++) {
      float term = (i == STOP_ || i == START_) ? NEG_ : (F[i] + trans[STOP_ * K_ + i]);
      if (term > best) { best = term; bi = i; }
    }
    out[0] = best;
    best_out[0] = bi;
  }
}

// vit_bp + chunkmap merged: bp replay, then per-chunk backtrace map G.
__global__ __launch_bounds__(64) void vit_bp(
    const float* __restrict__ feats, const float* __restrict__ trans,
    const float* __restrict__ Efv, unsigned char* __restrict__ bp,
    unsigned char* __restrict__ G)
{
  int cix = blockIdx.x, tid = threadIdx.x;
  __shared__ float tr[K_][K_];
  __shared__ float fe[CL_][K_];
  __shared__ float fv[K_], fvn[K_];
  __shared__ unsigned char bps[CL_][K_];
  for (int idx = tid; idx < K_ * K_; idx += 64) tr[idx / K_][idx % K_] = trans[idx];
  for (int idx = tid; idx < CL_ * K_; idx += 64)
    fe[idx / K_][idx % K_] = feats[cix * CL_ * K_ + idx];
  if (tid < K_) fv[tid] = Efv[cix * K_ + tid];
  __syncthreads();
  #pragma unroll 1
  for (int s = 0; s < CL_; s++) {
    if (tid < K_) {
      int i = tid;
      float best = fv[0] + tr[i][0]; int bj = 0;
      #pragma unroll
      for (int j = 1; j < K_; j++) {
        float v = fv[j] + tr[i][j];
        if (v > best) { best = v; bj = j; }
      }
      bp[(size_t)(cix * CL_ + s) * K_ + i] = (unsigned char)bj;
      bps[s][i] = (unsigned char)bj;
      fvn[i] = best + fe[s][i];
    }
    __syncthreads();
    if (tid < K_) fv[tid] = fvn[tid];
    __syncthreads();
  }
  if (tid < K_) {
    int tag = tid;
    #pragma unroll 1
    for (int s = CL_ - 1; s >= 0; s--) tag = bps[s][tag];
    G[cix * K_ + tid] = (unsigned char)tag;
  }
}

__global__ __launch_bounds__(64) void vit_bound(
    const unsigned char* __restrict__ G, const int* __restrict__ best,
    unsigned char* __restrict__ tbound)
{
  __shared__ unsigned char Gs[NC_][K_];
  int tid = threadIdx.x;
  for (int idx = tid; idx < NC_ * K_; idx += 64) Gs[idx / K_][idx % K_] = G[idx];
  __syncthreads();
  if (tid == 0) {
    int tag = best[0];
    tbound[NC_ - 1] = (unsigned char)tag;
    #pragma unroll 1
    for (int cix = NC_ - 1; cix >= 1; cix--) {
      tag = Gs[cix][tag];
      tbound[cix - 1] = (unsigned char)tag;
    }
  }
}

__global__ __launch_bounds__(64) void vit_path(
    const unsigned char* __restrict__ bp, const unsigned char* __restrict__ tbound,
    float* __restrict__ out)
{
  int cix = blockIdx.x, tid = threadIdx.x;
  __shared__ unsigned char bps[CL_][K_];
  for (int idx = tid; idx < CL_ * K_; idx += 64)
    bps[idx / K_][idx % K_] = bp[(size_t)cix * CL_ * K_ + idx];
  __syncthreads();
  if (tid == 0) {
    int tag = tbound[cix];
    out[1 + cix * CL_ + (CL_ - 1)] = (float)tag;
    #pragma unroll 1
    for (int s = CL_ - 1; s >= 1; s--) {
      tag = bps[s][tag];
      out[1 + cix * CL_ + s - 1] = (float)tag;
    }
  }
}

// ---------------------------------------------------------------------------
extern "C" void kernel_launch(void* const* d_in, const int* in_sizes, int n_in,
                              void* d_out, int out_size, void* d_ws, size_t ws_size,
                              hipStream_t stream) {
  const float* embeds = (const float*)d_in[0];
  const float* W_ih_f = (const float*)d_in[1];
  const float* W_hh_f = (const float*)d_in[2];
  const float* b_ih_f = (const float*)d_in[3];
  const float* b_hh_f = (const float*)d_in[4];
  const float* W_ih_b = (const float*)d_in[5];
  const float* W_hh_b = (const float*)d_in[6];
  const float* b_ih_b = (const float*)d_in[7];
  const float* b_hh_b = (const float*)d_in[8];
  const float* W_out  = (const float*)d_in[9];
  const float* b_out  = (const float*)d_in[10];
  const float* trans  = (const float*)d_in[11];
  float* out = (float*)d_out;

  char* ws = (char*)d_ws;
  size_t off = 0;
  float* xw_f = (float*)(ws + off); off += (size_t)N_ * G_ * 4;              // 26.2 MB
  float* xw_b = (float*)(ws + off); off += (size_t)N_ * G_ * 4;              // 26.2 MB
  bf16* Bh = (bf16*)(ws + off); off += (size_t)NT_ * KT_ * 512 * 2;          // 1.28 MB
  bf16* Bl = (bf16*)(ws + off); off += (size_t)NT_ * KT_ * 512 * 2;          // 1.28 MB
  // region R: Ah/Al live only until xw_mfma completes; post-GEMM buffers
  // alias the same region.
  char* R = ws + off;
  bf16* Ah = (bf16*)R;
  bf16* Al = (bf16*)(R + (size_t)MT_ * KT_ * 512 * 2);                       // +25.2 MB
  size_t ro = 0;
  float* hf   = (float*)(R + ro); ro += (size_t)N_ * H_ * 4;                 // 6.55 MB
  float* hb   = (float*)(R + ro); ro += (size_t)N_ * H_ * 4;                 // 6.55 MB
  float* feats= (float*)(R + ro); ro += (size_t)N_ * K_ * 4;                 // 655 KB
  float* Mall = (float*)(R + ro); ro += (size_t)NC_ * K_ * K_ * 4;
  float* Efv  = (float*)(R + ro); ro += (size_t)NC_ * K_ * 4;
  unsigned char* bp = (unsigned char*)(R + ro); ro += ((size_t)N_ * K_ + 255) & ~255ull;
  unsigned char* G  = (unsigned char*)(R + ro); ro += ((size_t)NC_ * K_ + 255) & ~255ull;
  unsigned char* tb = (unsigned char*)(R + ro); ro += 256;
  int* best = (int*)(R + ro); ro += 256;

  prep_A<<<MT_ * KT_ * 64 / 256, 256, 0, stream>>>(embeds, Ah, Al);
  prep_B<<<NT_ * KT_ * 64 / 256, 256, 0, stream>>>(W_ih_f, W_ih_b, Bh, Bl);
  xw_mfma<<<dim3(N_ / 64, 13), 256, 0, stream>>>(Ah, Al, Bh, Bl,
      b_ih_f, b_hh_f, b_ih_b, b_hh_b, xw_f, xw_b);
  lstm_rec<<<64, 832, 0, stream>>>(xw_f, xw_b, W_hh_f, W_hh_b, hf, hb);
  feats_kernel<<<(N_ * 16) / 256, 256, 0, stream>>>(hf, hb, W_out, b_out, feats);
  vit_chunkmat<<<NC_, 128, 0, stream>>>(feats, trans, Mall);
  vit_scan<<<1, 128, 0, stream>>>(Mall, trans, Efv, best, out);
  vit_bp<<<NC_, 64, 0, stream>>>(feats, trans, Efv, bp, G);
  vit_bound<<<1, 64, 0, stream>>>(G, best, tb);
  vit_path<<<NC_, 64, 0, stream>>>(bp, tb, out);
}